// Round 6
// baseline (85.565 us; speedup 1.0000x reference)
//
#include <hip/hip_runtime.h>

// GAT layer, B=4, N=256, IN=128, H=4, D=64 — SINGLE fused kernel.
//
// Exact index algebra (verified R0; R4 post-mortem: f1 must be indexed through
// the SAME scrambled flat layout as f2 — f1flat[hp*256+i], layout n*4+h):
//   e[b,hp,i,j] = lrelu_0.2( f1flat[hp*256 + i] + f2flat[(i&3)*256 + j] )
//   f1flat[n*4+hh] = h[b,n,:] . Wa1[:,hh],  Wa1[k][hh] = sum_d W[k,hh*64+d]*a[d]
//   f2flat[n*4+hh] = h[b,n,:] . Wa2[:,hh],  Wa2[k][hh] = sum_d W[k,hh*64+d]*a[64+d]
//   att = softmax_j(adj[b,i,j]==0 ? -inf : e)
//   out[b,i,hp*64+d] = sum_j att_norm * (h@W)[b,j,hp*64+d]
//                    = ((att @ h[b]) @ W[:, hp*64:+64]) * sinv    (assoc swap)
// grid 256 = (4b x 4hp x 16 row-tiles), 256 threads, 1 block/CU, no barrier.

__global__ __launch_bounds__(256) void gat_fused(
    const float* __restrict__ h, const float* __restrict__ W,
    const float* __restrict__ a, const int* __restrict__ adj,
    float* __restrict__ out)
{
  const int tid  = threadIdx.x;
  const int lane = tid & 63;
  const int wv   = tid >> 6;
  const int blk  = blockIdx.x;
  const int it = blk & 15, hp = (blk >> 4) & 3, b = blk >> 6;
  const int i0 = it * 16;

  __shared__ float Wa1s[128][4];   // 2 KB  per-head a1-contraction of W
  __shared__ float Wa2s[128][4];   // 2 KB  per-head a2-contraction of W
  __shared__ float f1s[1024];      // 4 KB  flat n*4+h
  __shared__ float f2s[1024];      // 4 KB  flat n*4+h
  __shared__ float att[16][256];   // 16 KB (rows 1024 B -> b128-aligned)
  __shared__ float Ps[16][128];    // 8 KB
  __shared__ float sinv[16];

  // ---------- P0: Wa1/Wa2[k][hh] = sum_d W[k,hh*64+d] * a[sel*64+d] ----------
  {
    const int k = tid >> 1, pair = tid & 1;         // heads 2*pair, 2*pair+1
    const float4* w4 = (const float4*)(W + k * 256 + pair * 128);
    const float4* a1 = (const float4*)a;
    const float4* a2 = (const float4*)(a + 64);
    float t0 = 0.f, t1 = 0.f, s0 = 0.f, s1 = 0.f;
#pragma unroll
    for (int d4 = 0; d4 < 16; d4++) {
      float4 x = w4[d4];
      float4 u = a1[d4], v = a2[d4];
      t0 += x.x*u.x + x.y*u.y + x.z*u.z + x.w*u.w;
      s0 += x.x*v.x + x.y*v.y + x.z*v.z + x.w*v.w;
    }
#pragma unroll
    for (int d4 = 0; d4 < 16; d4++) {
      float4 x = w4[16 + d4];
      float4 u = a1[d4], v = a2[d4];
      t1 += x.x*u.x + x.y*u.y + x.z*u.z + x.w*u.w;
      s1 += x.x*v.x + x.y*v.y + x.z*v.z + x.w*v.w;
    }
    Wa1s[k][pair * 2 + 0] = t0;
    Wa1s[k][pair * 2 + 1] = t1;
    Wa2s[k][pair * 2 + 0] = s0;
    Wa2s[k][pair * 2 + 1] = s1;
  }
  __syncthreads();

  // ---------- P1: f1s/f2s[n*4+hh] = h[b,n,:] . Wa{1,2}[:,hh] ------------------
  {
    const int n = tid;
    const float4* h4 = (const float4*)(h + (b * 256 + n) * 128);
    float d0=0.f, d1=0.f, d2=0.f, d3=0.f;      // f1
    float c0=0.f, c1=0.f, c2=0.f, c3=0.f;      // f2
    for (int k4 = 0; k4 < 32; k4++) {
      float4 hv = h4[k4];
      float4 xA = *(const float4*)&Wa1s[k4*4+0][0];
      float4 xB = *(const float4*)&Wa1s[k4*4+1][0];
      float4 xC = *(const float4*)&Wa1s[k4*4+2][0];
      float4 xD = *(const float4*)&Wa1s[k4*4+3][0];
      d0 += hv.x*xA.x + hv.y*xB.x + hv.z*xC.x + hv.w*xD.x;
      d1 += hv.x*xA.y + hv.y*xB.y + hv.z*xC.y + hv.w*xD.y;
      d2 += hv.x*xA.z + hv.y*xB.z + hv.z*xC.z + hv.w*xD.z;
      d3 += hv.x*xA.w + hv.y*xB.w + hv.z*xC.w + hv.w*xD.w;
      float4 wA = *(const float4*)&Wa2s[k4*4+0][0];
      float4 wB = *(const float4*)&Wa2s[k4*4+1][0];
      float4 wC = *(const float4*)&Wa2s[k4*4+2][0];
      float4 wD = *(const float4*)&Wa2s[k4*4+3][0];
      c0 += hv.x*wA.x + hv.y*wB.x + hv.z*wC.x + hv.w*wD.x;
      c1 += hv.x*wA.y + hv.y*wB.y + hv.z*wC.y + hv.w*wD.y;
      c2 += hv.x*wA.z + hv.y*wB.z + hv.z*wC.z + hv.w*wD.z;
      c3 += hv.x*wA.w + hv.y*wB.w + hv.z*wC.w + hv.w*wD.w;
    }
    float4 f1v = {d0, d1, d2, d3};
    float4 f2v = {c0, c1, c2, c3};
    *(float4*)&f1s[n * 4] = f1v;
    *(float4*)&f2s[n * 4] = f2v;
  }
  __syncthreads();

  // ---------- P2: masked softmax, wave wv builds rows wv*4..wv*4+3 -------------
#pragma unroll
  for (int rq = 0; rq < 4; rq++) {
    const int rr = wv * 4 + rq;
    const int i  = i0 + rr;
    const float s1 = f1s[hp * 256 + i];          // scrambled flat index (exact)
    const float* f2row = f2s + (i & 3) * 256;
    const int* adjrow = adj + (b * 256 + i) * 256;

    float e[4];
    float m = -1e30f;
#pragma unroll
    for (int jq = 0; jq < 4; jq++) {
      int j = lane + jq * 64;
      float ev = s1 + f2row[j];
      ev = ev > 0.f ? ev : 0.2f * ev;            // leaky relu 0.2
      ev = adjrow[j] ? ev : -1e30f;              // mask adj==0
      e[jq] = ev;
      m = fmaxf(m, ev);
    }
#pragma unroll
    for (int off = 32; off > 0; off >>= 1) m = fmaxf(m, __shfl_xor(m, off, 64));

    float s = 0.f;
#pragma unroll
    for (int jq = 0; jq < 4; jq++) {
      float ex = __expf(e[jq] - m);
      s += ex;
      att[rr][lane + jq * 64] = ex;
    }
#pragma unroll
    for (int off = 32; off > 0; off >>= 1) s += __shfl_xor(s, off, 64);
    if (lane == 0) sinv[rr] = 1.f / s;
  }
  __syncthreads();

  // ---------- P3: P = att(16x256) @ h[b](256x128) ------------------------------
  {
    const int k = tid & 127, ih = tid >> 7;      // ih: i-rows ih*8..ih*8+7
    const float* hb = h + b * 256 * 128 + k;     // h[b, j, k], j-stride 128
    float p[8] = {0.f,0.f,0.f,0.f,0.f,0.f,0.f,0.f};
    for (int j4 = 0; j4 < 64; j4++) {
      const int j = j4 * 4;
      float h0 = hb[(j+0)*128], h1 = hb[(j+1)*128];
      float h2 = hb[(j+2)*128], h3 = hb[(j+3)*128];
#pragma unroll
      for (int ii = 0; ii < 8; ii++) {
        float4 av = *(const float4*)&att[ih*8+ii][j];   // broadcast b128
        p[ii] += av.x*h0 + av.y*h1 + av.z*h2 + av.w*h3;
      }
    }
#pragma unroll
    for (int ii = 0; ii < 8; ii++) Ps[ih*8+ii][k] = p[ii];
  }
  __syncthreads();

  // ---------- P4: out-tile = (P @ W[:, hp*64:+64]) * sinv ----------------------
  {
    const int dd = tid & 63, iq = tid >> 6;      // i-rows iq*4..iq*4+3
    const float* wp = W + hp * 64 + dd;          // W[k, hp*64+dd], k-stride 256
    float acc0=0.f, acc1=0.f, acc2=0.f, acc3=0.f;
    for (int k4 = 0; k4 < 32; k4++) {
      const int k = k4 * 4;
      float w0 = wp[(k+0)*256], w1 = wp[(k+1)*256];
      float w2 = wp[(k+2)*256], w3 = wp[(k+3)*256];
      float4 p0 = *(const float4*)&Ps[iq*4+0][k];
      float4 p1 = *(const float4*)&Ps[iq*4+1][k];
      float4 p2 = *(const float4*)&Ps[iq*4+2][k];
      float4 p3 = *(const float4*)&Ps[iq*4+3][k];
      acc0 += p0.x*w0 + p0.y*w1 + p0.z*w2 + p0.w*w3;
      acc1 += p1.x*w0 + p1.y*w1 + p1.z*w2 + p1.w*w3;
      acc2 += p2.x*w0 + p2.y*w1 + p2.z*w2 + p2.w*w3;
      acc3 += p3.x*w0 + p3.y*w1 + p3.z*w2 + p3.w*w3;
    }
    float accs[4] = {acc0, acc1, acc2, acc3};
#pragma unroll
    for (int ii = 0; ii < 4; ii++) {
      const int r = iq * 4 + ii;
      out[(b * 256 + i0 + r) * 256 + hp * 64 + dd] = accs[ii] * sinv[r];
    }
  }
}

extern "C" void kernel_launch(void* const* d_in, const int* in_sizes, int n_in,
                              void* d_out, int out_size, void* d_ws, size_t ws_size,
                              hipStream_t stream) {
  const float* h   = (const float*)d_in[0];   // [4,256,128]
  const int*   adj = (const int*)d_in[1];     // [4,256,256]
  const float* W   = (const float*)d_in[2];   // [128,256]
  const float* a   = (const float*)d_in[3];   // [128,1]
  float* out = (float*)d_out;                 // [4,256,256]

  gat_fused<<<256, 256, 0, stream>>>(h, W, a, adj, out);
}

// Round 7
// 78.680 us; speedup vs baseline: 1.0875x; 1.0875x over previous
//
#include <hip/hip_runtime.h>

// GAT layer, B=4, N=256, IN=128, H=4, D=64 — SINGLE fused kernel, MFMA for the
// two per-block GEMMs (R6 post-mortem: broadcast ds_read_b128 = 16 B/12cyc was
// ~17 us of LDS pipe; MFMA collapses it).
//
// Exact index algebra (verified R0/R6):
//   e[b,hp,i,j] = lrelu_0.2( f1flat[hp*256+i] + f2flat[(i&3)*256+j] ), flat = n*4+h
//   f{1,2}flat[n*4+hh] = h[b,n,:] . Wa{1,2}[:,hh],  Wa{s}[k][hh]=sum_d W[k,hh*64+d]*a[(s-1)*64+d]
//   att = softmax_j(adj==0 ? -inf : e)
//   out[b,i,hp*64+d] = ((attU @ h[b]) @ W[:,hp*64:+64])[i][d] * sinv[i]
// grid 256 = (4b x 4hp x 16 row-tiles of 16), 256 threads, no global barrier.

typedef __attribute__((ext_vector_type(8))) short bf16x8;
typedef __attribute__((ext_vector_type(4))) float f32x4;

__device__ __forceinline__ short bf1(float x) {
  unsigned u = __builtin_bit_cast(unsigned, x);
  u = (u + 0x7FFFu + ((u >> 16) & 1u)) >> 16;        // RNE
  return (short)u;
}
__device__ __forceinline__ bf16x8 pack8(float4 a, float4 b) {
  bf16x8 r;
  r[0]=bf1(a.x); r[1]=bf1(a.y); r[2]=bf1(a.z); r[3]=bf1(a.w);
  r[4]=bf1(b.x); r[5]=bf1(b.y); r[6]=bf1(b.z); r[7]=bf1(b.w);
  return r;
}

__global__ __launch_bounds__(256) void gat_fused(
    const float* __restrict__ h, const float* __restrict__ W,
    const float* __restrict__ a, const int* __restrict__ adj,
    float* __restrict__ out)
{
  const int tid  = threadIdx.x;
  const int lane = tid & 63;
  const int quad = lane >> 4;        // MFMA quad 0..3
  const int col  = lane & 15;        // MFMA col/m 0..15
  const int wv   = tid >> 6;
  const int blk  = blockIdx.x;
  const int it = blk & 15, hp = (blk >> 4) & 3, b = blk >> 6;
  const int i0 = it * 16;

  __shared__ short WaTb[16][136];    // bf16, rows 0..3 = Wa1 heads, 4..7 = Wa2, 8..15 = 0
  __shared__ float f2s[1024];        // flat n*4+hh
  __shared__ float f1v[16];          // f1flat[hp*256 + i0 .. +15]
  __shared__ float att[16][260];     // +4 pad: 4-bank row offset
  __shared__ float Ps[16][132];      // P = attU @ h[b]
  __shared__ float sinv[16];

  // ---------- P0: Wa1/Wa2 -> bf16, transposed [c][k] -------------------------
  {
    const int k = tid >> 1, pair = tid & 1;           // heads 2p, 2p+1
    const float4* w4 = (const float4*)(W + k * 256 + pair * 128);
    const float4* a1 = (const float4*)a;
    const float4* a2 = (const float4*)(a + 64);
    float t0=0.f, t1=0.f, s0=0.f, s1=0.f;
#pragma unroll
    for (int d4 = 0; d4 < 16; d4++) {
      float4 x = w4[d4]; float4 u = a1[d4]; float4 v = a2[d4];
      t0 += x.x*u.x + x.y*u.y + x.z*u.z + x.w*u.w;
      s0 += x.x*v.x + x.y*v.y + x.z*v.z + x.w*v.w;
    }
#pragma unroll
    for (int d4 = 0; d4 < 16; d4++) {
      float4 x = w4[16 + d4]; float4 u = a1[d4]; float4 v = a2[d4];
      t1 += x.x*u.x + x.y*u.y + x.z*u.z + x.w*u.w;
      s1 += x.x*v.x + x.y*v.y + x.z*v.z + x.w*v.w;
    }
    WaTb[pair*2 + 0][k] = bf1(t0);
    WaTb[pair*2 + 1][k] = bf1(t1);
    WaTb[4 + pair*2 + 0][k] = bf1(s0);
    WaTb[4 + pair*2 + 1][k] = bf1(s1);
    int* zp = (int*)&WaTb[8][0];                      // zero rows 8..15
    for (int t = tid; t < 544; t += 256) zp[t] = 0;
  }
  __syncthreads();

  // ---------- P1: f = h[b](256x128) @ Wa(128x8pad16) via MFMA ----------------
  {
    bf16x8 bw[4];
#pragma unroll
    for (int kk = 0; kk < 4; kk++)
      bw[kk] = *(const bf16x8*)&WaTb[col][kk*32 + quad*8];
    const int mtstar = hp*4 + (it >> 2), qstar = it & 3;
#pragma unroll
    for (int q = 0; q < 4; q++) {
      const int mt = wv*4 + q, n0 = mt*16;
      const float* hrow = h + (b*256 + n0 + col)*128 + quad*8;
      f32x4 acc = {0.f, 0.f, 0.f, 0.f};
#pragma unroll
      for (int kk = 0; kk < 4; kk++) {
        float4 lo = *(const float4*)(hrow + kk*32);
        float4 hi = *(const float4*)(hrow + kk*32 + 4);
        acc = __builtin_amdgcn_mfma_f32_16x16x32_bf16(pack8(lo, hi), bw[kk], acc, 0, 0, 0);
      }
      if (col >= 4 && col < 8) {                       // f2 heads
#pragma unroll
        for (int r = 0; r < 4; r++) f2s[(n0 + quad*4 + r)*4 + (col - 4)] = acc[r];
      }
      if (mt == mtstar && col < 4 && quad == qstar) {  // the 16 f1 values needed
#pragma unroll
        for (int r = 0; r < 4; r++) f1v[r*4 + col] = acc[r];
      }
    }
  }
  __syncthreads();

  // ---------- P2: masked softmax, wave wv builds rows wv*4..+3 ---------------
#pragma unroll
  for (int rq = 0; rq < 4; rq++) {
    const int rr = wv*4 + rq;
    const int i  = i0 + rr;
    const float s1v = f1v[rr];
    const float* f2row = f2s + (i & 3)*256;
    const int* adjrow = adj + (b*256 + i)*256;
    float e[4];
    float m = -1e30f;
#pragma unroll
    for (int jq = 0; jq < 4; jq++) {
      int j = lane + jq*64;
      float ev = s1v + f2row[j];
      ev = ev > 0.f ? ev : 0.2f * ev;                  // leaky relu 0.2
      ev = adjrow[j] ? ev : -1e30f;                    // mask adj==0
      e[jq] = ev;
      m = fmaxf(m, ev);
    }
#pragma unroll
    for (int off = 32; off > 0; off >>= 1) m = fmaxf(m, __shfl_xor(m, off, 64));
    float s = 0.f;
#pragma unroll
    for (int jq = 0; jq < 4; jq++) {
      float ex = __expf(e[jq] - m);
      s += ex;
      att[rr][lane + jq*64] = ex;
    }
#pragma unroll
    for (int off = 32; off > 0; off >>= 1) s += __shfl_xor(s, off, 64);
    if (lane == 0) sinv[rr] = 1.f / s;
  }
  __syncthreads();

  // ---------- P3: P(16x128) = attU(16x256) @ h[b](256x128) via MFMA ----------
  {
    bf16x8 af[8];
    const float* arow = &att[col][quad*8];             // A: m=col, k=j
#pragma unroll
    for (int kk = 0; kk < 8; kk++)
      af[kk] = pack8(*(const float4*)(arow + kk*32),
                     *(const float4*)(arow + kk*32 + 4));
#pragma unroll
    for (int nt = 0; nt < 2; nt++) {
      const int ncol = wv*32 + nt*16 + col;            // output k-column
      const float* hcol = h + b*32768 + ncol + quad*8*128;
      f32x4 acc = {0.f, 0.f, 0.f, 0.f};
#pragma unroll
      for (int kk = 0; kk < 8; kk++) {
        const float* hq = hcol + kk*32*128;            // B[j][ncol], j-stride 128
        float4 lo = { hq[0],       hq[128],     hq[256],     hq[384] };
        float4 hi = { hq[512],     hq[640],     hq[768],     hq[896] };
        acc = __builtin_amdgcn_mfma_f32_16x16x32_bf16(af[kk], pack8(lo, hi), acc, 0, 0, 0);
      }
#pragma unroll
      for (int r = 0; r < 4; r++) Ps[quad*4 + r][wv*32 + nt*16 + col] = acc[r];
    }
  }
  __syncthreads();

  // ---------- P4: out-tile(16x64) = (P @ W[:,hp*64:+64]) * sinv, fp32 VALU ---
  {
    const int i = tid & 15, dq = tid >> 4;             // d = dq*4..+3
    const float4* w4 = (const float4*)W;               // idx k*64 + hp*16 + dq
    float4 acc = {0.f, 0.f, 0.f, 0.f};
    for (int k4 = 0; k4 < 32; k4++) {
      const int k = k4*4;
      float4 p  = *(const float4*)&Ps[i][k];
      float4 w0 = w4[(k+0)*64 + hp*16 + dq];
      float4 w1 = w4[(k+1)*64 + hp*16 + dq];
      float4 w2 = w4[(k+2)*64 + hp*16 + dq];
      float4 w3 = w4[(k+3)*64 + hp*16 + dq];
      acc.x += p.x*w0.x + p.y*w1.x + p.z*w2.x + p.w*w3.x;
      acc.y += p.x*w0.y + p.y*w1.y + p.z*w2.y + p.w*w3.y;
      acc.z += p.x*w0.z + p.y*w1.z + p.z*w2.z + p.w*w3.z;
      acc.w += p.x*w0.w + p.y*w1.w + p.z*w2.w + p.w*w3.w;
    }
    const float sv = sinv[i];
    float4 res = { acc.x*sv, acc.y*sv, acc.z*sv, acc.w*sv };
    *(float4*)&out[(b*256 + i0 + i)*256 + hp*64 + dq*4] = res;
  }
}

extern "C" void kernel_launch(void* const* d_in, const int* in_sizes, int n_in,
                              void* d_out, int out_size, void* d_ws, size_t ws_size,
                              hipStream_t stream) {
  const float* h   = (const float*)d_in[0];   // [4,256,128]
  const int*   adj = (const int*)d_in[1];     // [4,256,256]
  const float* W   = (const float*)d_in[2];   // [128,256]
  const float* a   = (const float*)d_in[3];   // [128,1]
  float* out = (float*)d_out;                 // [4,256,256]

  gat_fused<<<256, 256, 0, stream>>>(h, W, a, adj, out);
}

// Round 8
// 75.990 us; speedup vs baseline: 1.1260x; 1.0354x over previous
//
#include <hip/hip_runtime.h>

// GAT layer, B=4, N=256, IN=128, H=4, D=64 — single fused kernel, MFMA GEMMs,
// 512 threads/block (8 waves/CU) for latency hiding at ramp clocks.
//
// Exact index algebra (verified R0/R6/R7):
//   e[b,hp,i,j] = lrelu_0.2( f1flat[hp*256+i] + f2flat[(i&3)*256+j] ), flat = n*4+h
//   f{1,2}flat[n*4+hh] = h[b,n,:] . Wa{1,2}[:,hh],  Wa{s}[k][hh]=sum_d W[k,hh*64+d]*a[(s)*64+d]
//   att = softmax_j(adj==0 ? -inf : e)
//   out[b,i,hp*64+d] = ((attU @ h[b]) @ W[:,hp*64:+64])[i][d] * sinv[i]
// grid 256 = (4b x 4hp x 16 row-tiles of 16), no global barrier.

typedef __attribute__((ext_vector_type(8))) short bf16x8;
typedef __attribute__((ext_vector_type(4))) float f32x4;

__device__ __forceinline__ short bf1(float x) {
  unsigned u = __builtin_bit_cast(unsigned, x);
  u = (u + 0x7FFFu + ((u >> 16) & 1u)) >> 16;        // RNE
  return (short)u;
}
__device__ __forceinline__ bf16x8 pack8(float4 a, float4 b) {
  bf16x8 r;
  r[0]=bf1(a.x); r[1]=bf1(a.y); r[2]=bf1(a.z); r[3]=bf1(a.w);
  r[4]=bf1(b.x); r[5]=bf1(b.y); r[6]=bf1(b.z); r[7]=bf1(b.w);
  return r;
}

__global__ __launch_bounds__(512) void gat_fused(
    const float* __restrict__ h, const float* __restrict__ W,
    const float* __restrict__ a, const int* __restrict__ adj,
    float* __restrict__ out)
{
  const int tid  = threadIdx.x;
  const int lane = tid & 63;
  const int quad = lane >> 4;        // MFMA quad 0..3
  const int col  = lane & 15;        // MFMA col 0..15
  const int wv   = tid >> 6;         // wave 0..7
  const int blk  = blockIdx.x;
  const int it = blk & 15, hp = (blk >> 4) & 3, b = blk >> 6;
  const int i0 = it * 16;

  __shared__ short WaTb[16][136];    // bf16: rows 0..3 Wa1 heads, 4..7 Wa2, 8..15 zero
  __shared__ short WbT[64][136];     // bf16 W[:,hp*64:+64] transposed: [c][k]
  __shared__ float f2s[1024];        // flat n*4+hh
  __shared__ float f1v[16];          // f1flat[hp*256 + i0 .. +15]
  __shared__ short attb[16][264];    // bf16 unnormalized softmax rows
  __shared__ float Ps[16][132];      // P = attU @ h[b]
  __shared__ float sinv[16];

  // ---- prefetch adj for P2 (2 rows per wave) into registers -----------------
  int4 adjv[2];
#pragma unroll
  for (int rq = 0; rq < 2; rq++) {
    const int i = i0 + wv * 2 + rq;
    adjv[rq] = *(const int4*)(adj + (b * 256 + i) * 256 + lane * 4);
  }

  // ---------- P0a: Wa1/Wa2 -> bf16, transposed [hh][k] -----------------------
  {
    const int k = tid & 127, part = tid >> 7;       // part: sel<<1 | pair
    const int sel = part >> 1, pair = part & 1;     // heads 2*pair, 2*pair+1
    const float4* wrow = (const float4*)(W + k * 256 + pair * 128);
    const float4* ah = (const float4*)(a + sel * 64);
    float s0 = 0.f, s1 = 0.f;
#pragma unroll
    for (int d4 = 0; d4 < 16; d4++) {
      float4 x = wrow[d4]; float4 va = ah[d4];
      s0 += x.x*va.x + x.y*va.y + x.z*va.z + x.w*va.w;
    }
#pragma unroll
    for (int d4 = 0; d4 < 16; d4++) {
      float4 x = wrow[16 + d4]; float4 va = ah[d4];
      s1 += x.x*va.x + x.y*va.y + x.z*va.z + x.w*va.w;
    }
    const int row0 = sel * 4 + pair * 2;
    WaTb[row0 + 0][k] = bf1(s0);
    WaTb[row0 + 1][k] = bf1(s1);
    int* zp = (int*)&WaTb[8][0];                    // zero rows 8..15
    for (int t = tid; t < 544; t += 512) zp[t] = 0;
  }
  // ---------- P0b: stage WbT = bf16(W[:, hp*64:+64])^T, coalesced ------------
  {
#pragma unroll
    for (int q = 0; q < 4; q++) {
      const int idx = q * 512 + tid;                // 2048 float4 of the slice
      const int k = idx >> 4, c4 = idx & 15;
      float4 w4 = *(const float4*)(W + k * 256 + hp * 64 + c4 * 4);
      WbT[c4*4 + 0][k] = bf1(w4.x);
      WbT[c4*4 + 1][k] = bf1(w4.y);
      WbT[c4*4 + 2][k] = bf1(w4.z);
      WbT[c4*4 + 3][k] = bf1(w4.w);
    }
  }
  __syncthreads();

  // ---------- P1: f = h[b](256x128) @ Wa(128x8pad16) via MFMA ----------------
  {
    bf16x8 bw[4];
#pragma unroll
    for (int kk = 0; kk < 4; kk++)
      bw[kk] = *(const bf16x8*)&WaTb[col][kk*32 + quad*8];
    const int mtstar = hp*4 + (it >> 2), qstar = it & 3;
#pragma unroll
    for (int q = 0; q < 2; q++) {
      const int mt = wv*2 + q, n0 = mt*16;
      const float* hrow = h + (b*256 + n0 + col)*128 + quad*8;
      f32x4 acc = {0.f, 0.f, 0.f, 0.f};
#pragma unroll
      for (int kk = 0; kk < 4; kk++) {
        float4 lo = *(const float4*)(hrow + kk*32);
        float4 hi = *(const float4*)(hrow + kk*32 + 4);
        acc = __builtin_amdgcn_mfma_f32_16x16x32_bf16(pack8(lo, hi), bw[kk], acc, 0, 0, 0);
      }
      if (col >= 4 && col < 8) {                     // f2 heads
#pragma unroll
        for (int r = 0; r < 4; r++) f2s[(n0 + quad*4 + r)*4 + (col - 4)] = acc[r];
      }
      if (mt == mtstar && col < 4 && quad == qstar) {  // the 16 f1 values needed
#pragma unroll
        for (int r = 0; r < 4; r++) f1v[r*4 + col] = acc[r];
      }
    }
  }
  __syncthreads();

  // ---------- P2: masked softmax, wave wv builds rows wv*2, wv*2+1 -----------
#pragma unroll
  for (int rq = 0; rq < 2; rq++) {
    const int rr = wv*2 + rq;
    const int i  = i0 + rr;
    const float s1v = f1v[rr];
    float4 f2v = *(const float4*)(f2s + (i & 3)*256 + lane*4);
    const int4 av = adjv[rq];
    float e0 = s1v + f2v.x, e1 = s1v + f2v.y, e2 = s1v + f2v.z, e3 = s1v + f2v.w;
    e0 = e0 > 0.f ? e0 : 0.2f*e0;  e1 = e1 > 0.f ? e1 : 0.2f*e1;
    e2 = e2 > 0.f ? e2 : 0.2f*e2;  e3 = e3 > 0.f ? e3 : 0.2f*e3;
    e0 = av.x ? e0 : -1e30f;  e1 = av.y ? e1 : -1e30f;
    e2 = av.z ? e2 : -1e30f;  e3 = av.w ? e3 : -1e30f;
    float m = fmaxf(fmaxf(e0, e1), fmaxf(e2, e3));
#pragma unroll
    for (int off = 32; off > 0; off >>= 1) m = fmaxf(m, __shfl_xor(m, off, 64));
    float x0 = __expf(e0 - m), x1 = __expf(e1 - m);
    float x2 = __expf(e2 - m), x3 = __expf(e3 - m);
    float s = (x0 + x1) + (x2 + x3);
    float4 xa = {x0, x1, x2, x3};
    float4 xb = {0.f, 0.f, 0.f, 0.f};
    bf16x8 pk = pack8(xa, xb);
    *(int2*)&attb[rr][lane*4] = *(int2*)&pk;        // 4 bf16 = 8 B
#pragma unroll
    for (int off = 32; off > 0; off >>= 1) s += __shfl_xor(s, off, 64);
    if (lane == 0) sinv[rr] = 1.f / s;
  }
  __syncthreads();

  // ---------- P3: P(16x128) = attU(16x256) @ h[b](256x128), 1 n-tile/wave ----
  {
    bf16x8 af[8];
#pragma unroll
    for (int kk = 0; kk < 8; kk++)
      af[kk] = *(const bf16x8*)&attb[col][kk*32 + quad*8];
    const float* hcol = h + b*32768 + (wv*16 + col) + quad*8*128;
    f32x4 acc = {0.f, 0.f, 0.f, 0.f};
#pragma unroll
    for (int kk = 0; kk < 8; kk++) {
      const float* hq = hcol + kk*32*128;            // B[j][ncol], j-stride 128
      float4 lo = { hq[0],   hq[128], hq[256], hq[384] };
      float4 hi = { hq[512], hq[640], hq[768], hq[896] };
      acc = __builtin_amdgcn_mfma_f32_16x16x32_bf16(af[kk], pack8(lo, hi), acc, 0, 0, 0);
    }
#pragma unroll
    for (int r = 0; r < 4; r++) Ps[quad*4 + r][wv*16 + col] = acc[r];
  }
  __syncthreads();

  // ---------- P4: out(16x64) = (P @ Wslice) * sinv via MFMA, waves 0..3 ------
  if (wv < 4) {
    f32x4 acc = {0.f, 0.f, 0.f, 0.f};
#pragma unroll
    for (int kk = 0; kk < 4; kk++) {
      float4 lo = *(const float4*)&Ps[col][kk*32 + quad*8];
      float4 hi = *(const float4*)&Ps[col][kk*32 + quad*8 + 4];
      bf16x8 bp = *(const bf16x8*)&WbT[wv*16 + col][kk*32 + quad*8];
      acc = __builtin_amdgcn_mfma_f32_16x16x32_bf16(pack8(lo, hi), bp, acc, 0, 0, 0);
    }
#pragma unroll
    for (int r = 0; r < 4; r++) {
      const int m = quad*4 + r;
      out[(b*256 + i0 + m)*256 + hp*64 + wv*16 + col] = acc[r] * sinv[m];
    }
  }
}

extern "C" void kernel_launch(void* const* d_in, const int* in_sizes, int n_in,
                              void* d_out, int out_size, void* d_ws, size_t ws_size,
                              hipStream_t stream) {
  const float* h   = (const float*)d_in[0];   // [4,256,128]
  const int*   adj = (const int*)d_in[1];     // [4,256,256]
  const float* W   = (const float*)d_in[2];   // [128,256]
  const float* a   = (const float*)d_in[3];   // [128,1]
  float* out = (float*)d_out;                 // [4,256,256]

  gat_fused<<<256, 512, 0, stream>>>(h, W, a, adj, out);
}